// Round 1
// baseline (622.298 us; speedup 1.0000x reference)
//
#include <hip/hip_runtime.h>

// cLSTM fused single-step: h=c=c_target=0  =>
//   g5 = x[16384,1024] @ W5[1024, 5*1024] + b5   (gates i, it, z, o, d; f/ft dead)
//   epilogue: sigmoid/softplus/tanh -> 5 outputs [B,H] f32 each.
// R3: double-buffered LDS pipeline (stage-next-first, 1 barrier/k-step),
//     XOR granule swizzle (slot^=row&3) to balance LDS bank halves,
//     nontemporal output stores (stop L3 thrash of wt/xb),
//     XCD n-banded tile remap, setprio around MFMA cluster,
//     hoisted per-wave staging base pointers.

#define B_SZ 16384
#define H_SZ 1024
#define K_SZ 1024
#define BH ((size_t)B_SZ * H_SZ)
#define NGATE 5
#define CHUNK 512              // ushorts per 16x32 staging chunk (1 KB)
#define BUFU (28 * CHUNK)      // 14336 ushorts = 28 KB per buffer

typedef __bf16 bf16x8 __attribute__((ext_vector_type(8)));
typedef float f32x4 __attribute__((ext_vector_type(4)));

__device__ __forceinline__ unsigned short f2bf(float f) {
    unsigned int u = __float_as_uint(f);
    u += 0x7FFFu + ((u >> 16) & 1u);   // round-to-nearest-even
    return (unsigned short)(u >> 16);
}

__device__ __forceinline__ float rcp_fast(float x) { return __builtin_amdgcn_rcpf(x); }
__device__ __forceinline__ float sigm(float x) { return rcp_fast(1.f + __expf(-x)); }
__device__ __forceinline__ float softplus_f(float x) {
    return fmaxf(x, 0.f) + __logf(1.f + __expf(-fabsf(x)));
}
__device__ __forceinline__ float tanh_f(float x) {
    float e = __expf(2.f * x);          // cell in (-1,1): stable
    return (e - 1.f) * rcp_fast(e + 1.f);
}

// ---- pass 1a: x f32 -> bf16 (coalesced, 4 elems/thread) ----
__global__ void conv_x_kernel(const float* __restrict__ x, unsigned short* __restrict__ xb) {
    int i = blockIdx.x * blockDim.x + threadIdx.x;
    float4 v = ((const float4*)x)[i];
    ushort4 o;
    o.x = f2bf(v.x); o.y = f2bf(v.y); o.z = f2bf(v.z); o.w = f2bf(v.w);
    ((ushort4*)xb)[i] = o;
}

// ---- pass 1b: W[k,n] (first 1024 k-rows only) -> Wt[g][n][k] bf16 ----
__global__ void conv_w_kernel(const float* __restrict__ W0, const float* __restrict__ W1,
                              const float* __restrict__ W2, const float* __restrict__ W3,
                              const float* __restrict__ W4, unsigned short* __restrict__ wt) {
    const float* Ws[NGATE] = {W0, W1, W2, W3, W4};
    const float* W = Ws[blockIdx.z];
    __shared__ float tile[64][65];
    const int k0 = blockIdx.x * 64, n0 = blockIdx.y * 64;
    const int tid = threadIdx.x;
    {
        const int kk = tid >> 6, nn = tid & 63;
#pragma unroll
        for (int rr = 0; rr < 16; rr++) {
            const int row = kk * 16 + rr;
            tile[row][nn] = W[(size_t)(k0 + row) * H_SZ + n0 + nn];
        }
    }
    __syncthreads();
    unsigned short* out = wt + (size_t)blockIdx.z * H_SZ * K_SZ;
    {
        const int nrow = tid >> 2, kq = (tid & 3) * 16;
#pragma unroll
        for (int j = 0; j < 4; j++) {
            const int k = kq + j * 4;
            ushort4 v;
            v.x = f2bf(tile[k + 0][nrow]);
            v.y = f2bf(tile[k + 1][nrow]);
            v.z = f2bf(tile[k + 2][nrow]);
            v.w = f2bf(tile[k + 3][nrow]);
            *(ushort4*)&out[(size_t)(n0 + nrow) * K_SZ + k0 + k] = v;
        }
    }
}

// ---- pass 2: fused 5-gate GEMM + epilogue ----
// block tile 128(m) x 64(n), 4 waves (wm 0..1 x wn 0..1), each wave 64x32 per gate.
// LDS: 2 x (A[128][32] + B[5][64][32]) bf16 = 56 KB, double-buffered,
// staged via global_load_lds w=16 with XOR-swizzled source (slot ^= row&3).
__global__ __launch_bounds__(256, 2) void fused_clstm_kernel(
    const unsigned short* __restrict__ xb,   // [16384][1024] bf16
    const unsigned short* __restrict__ wt,   // [5][1024 n][1024 k] bf16
    const float* __restrict__ bi, const float* __restrict__ bit_,
    const float* __restrict__ bz, const float* __restrict__ bo,
    const float* __restrict__ bd,
    const float* __restrict__ t, const float* __restrict__ last_t,
    float* __restrict__ out)
{
    __shared__ unsigned short smem[2 * BUFU];

    const int tid  = threadIdx.x;
    const int wave = tid >> 6;
    const int lane = tid & 63;
    const int quad = lane >> 4;
    const int l16  = lane & 15;
    const int wm   = wave >> 1;      // 0..1 -> m-half (64 rows)
    const int wn   = wave & 1;       // 0..1 -> n-half (32 cols)

    // XCD-banded tile remap: dispatch slot s -> XCD s&7; each XCD owns
    // 2 n-blocks x 128 m-blocks so its 640 KiB wt slice stays L2-hot.
    const int s     = blockIdx.y * 16 + blockIdx.x;   // 0..2047
    const int xcd   = s & 7;
    const int jj    = s >> 3;                          // 0..255
    const int n_blk = xcd * 2 + (jj >> 7);             // 0..15
    const int m_blk = jj & 127;                        // 0..127
    const int m0    = m_blk * 128;
    const int n0    = n_blk * 64;

    // staging lane mapping: row = lane>>2 (within 16-row chunk),
    // source k-slot XOR-swizzled so reads are bank-balanced per half-wave.
    const int srow = lane >> 2;
    const int scol = ((lane & 3) ^ (srow & 3)) * 8;    // elements (16 B granule)
    const int xq   = (quad ^ (l16 & 3)) * 8;           // read-side same involution

    // per-wave global staging base pointers (k=0); hot loop only adds k-offset
    const unsigned short* gbase[7];
#pragma unroll
    for (int i = 0; i < 7; i++) {
        const int c = wave * 7 + i;    // 0..27: 0-7 = A (128 rows), 8.. = B gate (c-8)/4
        if (c < 8) {
            gbase[i] = xb + (size_t)(m0 + c * 16 + srow) * K_SZ + scol;
        } else {
            const int g = (c - 8) >> 2, q = (c - 8) & 3;
            gbase[i] = wt + (size_t)g * H_SZ * K_SZ
                          + (size_t)(n0 + q * 16 + srow) * K_SZ + scol;
        }
    }

    f32x4 acc[NGATE][4][2];
#pragma unroll
    for (int g = 0; g < NGATE; g++)
#pragma unroll
        for (int mf = 0; mf < 4; mf++)
#pragma unroll
            for (int nf = 0; nf < 2; nf++)
                acc[g][mf][nf] = (f32x4){0.f, 0.f, 0.f, 0.f};

#define STAGE(bufi, kk) do {                                                          \
    _Pragma("unroll")                                                                 \
    for (int i = 0; i < 7; i++) {                                                     \
        __builtin_amdgcn_global_load_lds(                                             \
            (const __attribute__((address_space(1))) unsigned int*)(gbase[i] + (kk)), \
            (__attribute__((address_space(3))) unsigned int*)                         \
                (&smem[(bufi) * BUFU + (wave * 7 + i) * CHUNK + lane * 8]),           \
            16, 0, 0);                                                                \
    } } while (0)

#define COMPUTE(bufi) do {                                                            \
    const unsigned short* sb_ = &smem[(bufi) * BUFU];                                 \
    bf16x8 a_[4];                                                                     \
    _Pragma("unroll")                                                                 \
    for (int mf = 0; mf < 4; mf++)                                                    \
        a_[mf] = *(const bf16x8*)(&sb_[(wm * 64 + mf * 16 + l16) * 32 + xq]);         \
    __builtin_amdgcn_s_setprio(1);                                                    \
    _Pragma("unroll")                                                                 \
    for (int g = 0; g < NGATE; g++) {                                                 \
        const unsigned short* bs_ = &sb_[(8 + g * 4) * CHUNK];                        \
        const bf16x8 b0 = *(const bf16x8*)(&bs_[(wn * 32      + l16) * 32 + xq]);     \
        const bf16x8 b1 = *(const bf16x8*)(&bs_[(wn * 32 + 16 + l16) * 32 + xq]);     \
        _Pragma("unroll")                                                             \
        for (int mf = 0; mf < 4; mf++) {                                              \
            acc[g][mf][0] = __builtin_amdgcn_mfma_f32_16x16x32_bf16(a_[mf], b0, acc[g][mf][0], 0, 0, 0); \
            acc[g][mf][1] = __builtin_amdgcn_mfma_f32_16x16x32_bf16(a_[mf], b1, acc[g][mf][1], 0, 0, 0); \
        } }                                                                           \
    __builtin_amdgcn_s_setprio(0); } while (0)

    // ---- pipelined K loop: stage(next) issued before compute(cur);
    //      the vmcnt(0) drain inside __syncthreads() lands a full compute
    //      phase after issue instead of immediately after.
    STAGE(0, 0);
    __syncthreads();

#pragma unroll 1
    for (int k0 = 0; k0 < K_SZ - 64; k0 += 64) {
        STAGE(1, k0 + 32);
        __builtin_amdgcn_sched_barrier(0);
        COMPUTE(0);                       // step k0
        __syncthreads();
        STAGE(0, k0 + 64);
        __builtin_amdgcn_sched_barrier(0);
        COMPUTE(1);                       // step k0+32
        __syncthreads();
    }
    // tail: buf0 holds k=960 (staged in last loop iter); stage 992, finish both.
    STAGE(1, K_SZ - 32);
    __builtin_amdgcn_sched_barrier(0);
    COMPUTE(0);                           // step 960
    __syncthreads();
    COMPUTE(1);                           // step 992
#undef STAGE
#undef COMPUTE

    // ---- epilogue: C/D layout col = l16, row = quad*4 + reg ----
    const float* biasp[NGATE] = {bi, bit_, bz, bo, bd};
    float bv[NGATE][2];
#pragma unroll
    for (int g = 0; g < NGATE; g++)
#pragma unroll
        for (int nf = 0; nf < 2; nf++)
            bv[g][nf] = biasp[g][n0 + wn * 32 + nf * 16 + l16];

#pragma unroll
    for (int mf = 0; mf < 4; mf++) {
#pragma unroll
        for (int r = 0; r < 4; r++) {
            const int brow = m0 + wm * 64 + mf * 16 + quad * 4 + r;
            const float dt = t[brow] - last_t[brow];
#pragma unroll
            for (int nf = 0; nf < 2; nf++) {
                const int ncol = n0 + wn * 32 + nf * 16 + l16;
                const float gi  = acc[0][mf][nf][r] + bv[0][nf];
                const float git = acc[1][mf][nf][r] + bv[1][nf];
                const float gz  = acc[2][mf][nf][r] + bv[2][nf];
                const float go  = acc[3][mf][nf][r] + bv[3][nf];
                const float gd  = acc[4][mf][nf][r] + bv[4][nf];

                const float gate_i  = sigm(gi);
                const float gate_it = sigm(git);
                const float z       = 2.f * sigm(gz) - 1.f;
                const float gate_o  = sigm(go);
                const float delta   = softplus_f(gd);

                const float c_n  = gate_i  * z;     // gate_f * 0 + gate_i * z
                const float ct_n = gate_it * z;
                const float cell = ct_n + (c_n - ct_n) * __expf(-delta * dt);
                const float h_n  = gate_o * tanh_f(cell);

                const size_t idx = (size_t)brow * H_SZ + ncol;
                // streaming outputs: never re-read -> nontemporal, keep wt/xb in L3
                __builtin_nontemporal_store(h_n,    &out[idx]);
                __builtin_nontemporal_store(c_n,    &out[BH + idx]);
                __builtin_nontemporal_store(ct_n,   &out[2 * BH + idx]);
                __builtin_nontemporal_store(gate_o, &out[3 * BH + idx]);
                __builtin_nontemporal_store(delta,  &out[4 * BH + idx]);
            }
        }
    }
}

extern "C" void kernel_launch(void* const* d_in, const int* in_sizes, int n_in,
                              void* d_out, int out_size, void* d_ws, size_t ws_size,
                              hipStream_t stream) {
    const float* x      = (const float*)d_in[0];
    // d_in[1] = n_id (unused by reference math)
    const float* t      = (const float*)d_in[2];
    const float* last_t = (const float*)d_in[3];
    const float* Wi  = (const float*)d_in[4];
    const float* bi  = (const float*)d_in[5];
    const float* Wit = (const float*)d_in[6];
    const float* bit_= (const float*)d_in[7];
    // d_in[8..11] = Wf, bf, Wft, bft : dead (multiply zero state)
    const float* Wz  = (const float*)d_in[12];
    const float* bz  = (const float*)d_in[13];
    const float* Wo  = (const float*)d_in[14];
    const float* bo  = (const float*)d_in[15];
    const float* Wd  = (const float*)d_in[16];
    const float* bd  = (const float*)d_in[17];

    unsigned short* xb = (unsigned short*)d_ws;                 // 32 MiB
    unsigned short* wt = xb + (size_t)B_SZ * K_SZ;              // + 10 MiB

    conv_x_kernel<<<(B_SZ * K_SZ / 4) / 256, 256, 0, stream>>>(x, xb);

    dim3 gw(16, 16, NGATE);
    conv_w_kernel<<<gw, 256, 0, stream>>>(Wi, Wit, Wz, Wo, Wd, wt);

    dim3 gm(H_SZ / 64, B_SZ / 128);   // (16, 128)
    fused_clstm_kernel<<<gm, 256, 0, stream>>>(xb, wt, bi, bit_, bz, bo, bd,
                                               t, last_t, (float*)d_out);
}